// Round 5
// baseline (120.922 us; speedup 1.0000x reference)
//
#include <hip/hip_runtime.h>
#include <hip/hip_bf16.h>
#include <math.h>

#define MC_    10
#define IN_C_  16
#define OUT_C_ 32
#define K_     3
#define D_     144
#define KP_    160                 // K padded to 5 x 32
#define H_     128
#define W_     128
#define HW_    64
#define B_     8
#define MCG_   2                   // mc per block
#define NMCG_  (MC_ / MCG_)        // 5 mc-groups

typedef __attribute__((ext_vector_type(8))) short short8;   // 8 bf16 = 4 VGPR
typedef __attribute__((ext_vector_type(4))) float f32x4;

static __device__ __forceinline__ unsigned short f2bf(float v) {
    union { float f; unsigned u; } x; x.f = v;
    unsigned r = x.u + 0x7fff + ((x.u >> 16) & 1);           // RNE
    return (unsigned short)(r >> 16);
}

// ---------------------------------------------------------------------------
// Kernel 1: reparameterize + transpose + bf16-cast weights into d_ws:
//   W2[mc][oc][k] (k padded to 160, zeros for k>=144), k = (kh*3+kw)*16+ic
// ---------------------------------------------------------------------------
__global__ __launch_bounds__(256) void prep_w_kernel(
    const float* __restrict__ eps, const float* __restrict__ logsig,
    const float* __restrict__ mean, unsigned short* __restrict__ w2)
{
    int i = blockIdx.x * 256 + threadIdx.x;      // over 10*32*160 = 51200
    if (i >= MC_ * OUT_C_ * KP_) return;
    int k  = i % KP_;
    int oc = (i / KP_) % OUT_C_;
    int mc = i / (KP_ * OUT_C_);
    float val = 0.0f;
    if (k < D_) {
        int doc = k * OUT_C_ + oc;
        val = eps[mc * (D_ * OUT_C_) + doc] * __expf(0.5f * logsig[doc]) + mean[doc];
    }
    w2[i] = f2bf(val);
}

// ---------------------------------------------------------------------------
// Kernel 2: implicit-GEMM conv via bf16 MFMA + RFF epilogue.
// grid = (128 m-tiles, 8 b, 5 mc-groups); block = 256 = 4 waves
// (2 oc-tiles x 2 px-tiles). Tile: 32 px x 32 oc x 2 mc.
// mc-split x5 vs R4: 5120 blocks (~8 resident blocks/CU) to hide the
// im2col load chain + per-mc L2 weight latency + store drain.
// Weights are MFMA A, pixels B -> C col = pixel -> coalesced direct stores.
// ---------------------------------------------------------------------------
__global__ __launch_bounds__(256) void conv_rff_mfma(
    const float* __restrict__ x,              // [B][16][128][128]
    const unsigned short* __restrict__ w2,    // [MC][32][160] bf16
    const float* __restrict__ theta,
    float* __restrict__ out)                  // [B][640][64][64]
{
    __shared__ __align__(16) unsigned short Alds[32 * 168];  // im2col, stride 168

    const int tid  = threadIdx.x;
    const int tile = blockIdx.x;              // 0..127
    const int b    = blockIdx.y;
    const int mc0  = blockIdx.z * MCG_;       // 0,2,4,6,8
    const int oh   = tile >> 1;
    const int ow0  = (tile & 1) << 5;
    const float* __restrict__ xb = x + (size_t)b * (IN_C_ * H_ * W_);

    // ---- im2col: A[px=0..31][k=0..159]; batch loads first (all in flight) ----
    float v[20];
#pragma unroll
    for (int j = 0; j < 20; ++j) {
        int idx = j * 256 + tid;              // 0..5119
        int m = idx & 31;
        int k = idx >> 5;                     // 0..159
        float val = 0.0f;
        if (k < D_) {
            int ic = k & 15;
            int t  = k >> 4;                  // 0..8
            int kh = (t * 11) >> 5;           // t/3
            int kw = t - kh * 3;
            int ih = oh * 2 - 1 + kh;
            int iw = (ow0 + m) * 2 - 1 + kw;
            if ((unsigned)ih < (unsigned)H_ && (unsigned)iw < (unsigned)W_)
                val = xb[ic * (H_ * W_) + ih * W_ + iw];
        }
        v[j] = val;
    }
#pragma unroll
    for (int j = 0; j < 20; ++j) {
        int idx = j * 256 + tid;
        Alds[(idx & 31) * 168 + (idx >> 5)] = f2bf(v[j]);
    }
    __syncthreads();

    const int lane  = tid & 63;
    const int wave  = tid >> 6;
    const int wn_oc = (wave & 1) << 4;        // oc-tile offset:    0 / 16
    const int wm_px = (wave >> 1) << 4;       // pixel-tile offset: 0 / 16
    const int l15   = lane & 15;
    const int quad  = lane >> 4;

    // Pixel (B) fragments: lane holds B[k = quad*8 + j][n = l15] = im2col[px][k]
    short8 pf[5];
#pragma unroll
    for (int ks = 0; ks < 5; ++ks)
        pf[ks] = *(const short8*)&Alds[(wm_px + l15) * 168 + ks * 32 + quad * 8];

    // Weight (A) fragments for BOTH mc of this group, prefetched up front:
    // lane holds A[m = l15][k = quad*8 + j] = W2[mc][oc][k]
    short8 wf[MCG_][5];
#pragma unroll
    for (int g = 0; g < MCG_; ++g) {
        const unsigned short* __restrict__ wmc =
            w2 + (size_t)(mc0 + g) * (OUT_C_ * KP_);
#pragma unroll
        for (int ks = 0; ks < 5; ++ks)
            wf[g][ks] = *(const short8*)&wmc[(wn_oc + l15) * KP_ + ks * 32 + quad * 8];
    }

    const float scale = __expf(0.5f * theta[0]) * rsqrtf((float)(OUT_C_ * HW_ * HW_));

    // out[b][ch][oh][ow0 + wm_px + px]; per-quad 16 lanes -> 64B segments
    float* __restrict__ po =
        out + (size_t)b * (MC_ * 2 * OUT_C_ * HW_ * HW_) + oh * HW_ + ow0 + wm_px + l15;

#pragma unroll
    for (int g = 0; g < MCG_; ++g) {
        f32x4 acc = {0.f, 0.f, 0.f, 0.f};
#pragma unroll
        for (int ks = 0; ks < 5; ++ks)
            acc = __builtin_amdgcn_mfma_f32_16x16x32_bf16(wf[g][ks], pf[ks], acc, 0, 0, 0);

        // C layout: col = l15 = pixel, row = quad*4 + r = oc (16x16 tile)
        const int ch0 = (mc0 + g) * (2 * OUT_C_) + wn_oc + quad * 4;  // cos chans
#pragma unroll
        for (int r = 0; r < 4; ++r) {
            float s, c;
            __sincosf(acc[r], &s, &c);
            po[(size_t)(ch0 + r) * (HW_ * HW_)]           = scale * c;
            po[(size_t)(ch0 + r + OUT_C_) * (HW_ * HW_)]  = scale * s;
        }
    }
}

// ---------------------------------------------------------------------------
extern "C" void kernel_launch(void* const* d_in, const int* in_sizes, int n_in,
                              void* d_out, int out_size, void* d_ws, size_t ws_size,
                              hipStream_t stream)
{
    const float* x      = (const float*)d_in[0];  // (8,16,128,128)
    const float* theta  = (const float*)d_in[1];  // (1,)
    const float* mean   = (const float*)d_in[2];  // (144,32)
    const float* logsig = (const float*)d_in[3];  // (144,32)
    const float* eps    = (const float*)d_in[4];  // (10,144,32)
    float* out = (float*)d_out;
    unsigned short* W2 = (unsigned short*)d_ws;   // 51200 bf16 = 100 KB

    const int n_w = MC_ * OUT_C_ * KP_;           // 51200
    prep_w_kernel<<<(n_w + 255) / 256, 256, 0, stream>>>(eps, logsig, mean, W2);

    dim3 grid(128, B_, NMCG_);                    // 5120 blocks
    conv_rff_mfma<<<grid, 256, 0, stream>>>(x, W2, theta, out);
}

// Round 6
// 110.593 us; speedup vs baseline: 1.0934x; 1.0934x over previous
//
#include <hip/hip_runtime.h>
#include <hip/hip_bf16.h>
#include <math.h>

#define MC_    10
#define IN_C_  16
#define OUT_C_ 32
#define K_     3
#define D_     144
#define KP_    160                 // K padded to 5 x 32
#define H_     128
#define W_     128
#define HW_    64
#define B_     8

typedef __attribute__((ext_vector_type(8))) short short8;   // 8 bf16 = 4 VGPR
typedef __attribute__((ext_vector_type(4))) float f32x4;

static __device__ __forceinline__ unsigned short f2bf(float v) {
    union { float f; unsigned u; } x; x.f = v;
    unsigned r = x.u + 0x7fff + ((x.u >> 16) & 1);           // RNE
    return (unsigned short)(r >> 16);
}

// ---------------------------------------------------------------------------
// Kernel 1: reparameterize + transpose + bf16-cast weights into d_ws:
//   W2[mc][oc][k] (k padded to 160, zeros for k>=144), k = (kh*3+kw)*16+ic
// ---------------------------------------------------------------------------
__global__ __launch_bounds__(256) void prep_w_kernel(
    const float* __restrict__ eps, const float* __restrict__ logsig,
    const float* __restrict__ mean, unsigned short* __restrict__ w2)
{
    int i = blockIdx.x * 256 + threadIdx.x;      // over 10*32*160 = 51200
    if (i >= MC_ * OUT_C_ * KP_) return;
    int k  = i % KP_;
    int oc = (i / KP_) % OUT_C_;
    int mc = i / (KP_ * OUT_C_);
    float val = 0.0f;
    if (k < D_) {
        int doc = k * OUT_C_ + oc;
        val = eps[mc * (D_ * OUT_C_) + doc] * __expf(0.5f * logsig[doc]) + mean[doc];
    }
    w2[i] = f2bf(val);
}

// ---------------------------------------------------------------------------
// Kernel 2: implicit-GEMM conv via bf16 MFMA + RFF epilogue.
// grid = (128, 8) = 1024 blocks, fully co-resident (4 blocks/CU).
// XCD-aware remap: XCD = linear_block % 8 and 128 % 8 == 0, so b = bx & 7
// pins each batch to one XCD; during each mc-phase an XCD's writes cover one
// contiguous ~1MB (64ch x 16KB) slice of its own batch -> L2 assembles full
// 16KB channel chunks before eviction (fixes 128B HBM write scatter).
// Block tile: 32 px (one oh half-row) x 32 oc x all 10 mc.
// Weights are MFMA A, pixels B -> C col = pixel -> coalesced direct stores.
// ---------------------------------------------------------------------------
__global__ __launch_bounds__(256) void conv_rff_mfma(
    const float* __restrict__ x,              // [B][16][128][128]
    const unsigned short* __restrict__ w2,    // [MC][32][160] bf16
    const float* __restrict__ theta,
    float* __restrict__ out)                  // [B][640][64][64]
{
    __shared__ __align__(16) unsigned short Alds[32 * 168];  // im2col, stride 168

    const int tid  = threadIdx.x;
    const int bx   = blockIdx.x;              // 0..127
    const int by   = blockIdx.y;              // 0..7
    const int b    = bx & 7;                  // batch pinned to XCD (= gid % 8)
    const int t    = (bx >> 3) + 16 * by;     // 0..127 tile within batch
    const int oh   = t >> 1;
    const int ow0  = (t & 1) << 5;
    const float* __restrict__ xb = x + (size_t)b * (IN_C_ * H_ * W_);

    // ---- im2col: A[px=0..31][k=0..159]; batch loads first (all in flight) ----
    float v[20];
#pragma unroll
    for (int j = 0; j < 20; ++j) {
        int idx = j * 256 + tid;              // 0..5119
        int m = idx & 31;
        int k = idx >> 5;                     // 0..159
        float val = 0.0f;
        if (k < D_) {
            int ic = k & 15;
            int tt = k >> 4;                  // 0..8
            int kh = (tt * 11) >> 5;          // tt/3
            int kw = tt - kh * 3;
            int ih = oh * 2 - 1 + kh;
            int iw = (ow0 + m) * 2 - 1 + kw;
            if ((unsigned)ih < (unsigned)H_ && (unsigned)iw < (unsigned)W_)
                val = xb[ic * (H_ * W_) + ih * W_ + iw];
        }
        v[j] = val;
    }
#pragma unroll
    for (int j = 0; j < 20; ++j) {
        int idx = j * 256 + tid;
        Alds[(idx & 31) * 168 + (idx >> 5)] = f2bf(v[j]);
    }
    __syncthreads();

    const int lane  = tid & 63;
    const int wave  = tid >> 6;
    const int wn_oc = (wave & 1) << 4;        // oc-tile offset:    0 / 16
    const int wm_px = (wave >> 1) << 4;       // pixel-tile offset: 0 / 16
    const int l15   = lane & 15;
    const int quad  = lane >> 4;

    // Pixel (B) fragments: lane holds B[k = quad*8 + j][n = l15] = im2col[px][k]
    short8 pf[5];
#pragma unroll
    for (int ks = 0; ks < 5; ++ks)
        pf[ks] = *(const short8*)&Alds[(wm_px + l15) * 168 + ks * 32 + quad * 8];

    const float scale = __expf(0.5f * theta[0]) * rsqrtf((float)(OUT_C_ * HW_ * HW_));

    // out[b][ch][oh][ow0 + wm_px + px]; per-quad 16 lanes -> 64B segments
    float* __restrict__ po =
        out + (size_t)b * (MC_ * 2 * OUT_C_ * HW_ * HW_) + oh * HW_ + ow0 + wm_px + l15;

    for (int mc = 0; mc < MC_; ++mc) {
        // Weight (A) fragments: lane holds A[m = l15][k = quad*8 + j] = W2[oc][k]
        const unsigned short* __restrict__ wmc = w2 + (size_t)mc * (OUT_C_ * KP_);
        short8 wf[5];
#pragma unroll
        for (int ks = 0; ks < 5; ++ks)
            wf[ks] = *(const short8*)&wmc[(wn_oc + l15) * KP_ + ks * 32 + quad * 8];

        f32x4 acc = {0.f, 0.f, 0.f, 0.f};
#pragma unroll
        for (int ks = 0; ks < 5; ++ks)
            acc = __builtin_amdgcn_mfma_f32_16x16x32_bf16(wf[ks], pf[ks], acc, 0, 0, 0);

        // C layout: col = l15 = pixel, row = quad*4 + r = oc (16x16 tile)
        const int ch0 = mc * (2 * OUT_C_) + wn_oc + quad * 4;   // cos channels
#pragma unroll
        for (int r = 0; r < 4; ++r) {
            float s, c;
            __sincosf(acc[r], &s, &c);
            po[(size_t)(ch0 + r) * (HW_ * HW_)]           = scale * c;
            po[(size_t)(ch0 + r + OUT_C_) * (HW_ * HW_)]  = scale * s;
        }
    }
}

// ---------------------------------------------------------------------------
extern "C" void kernel_launch(void* const* d_in, const int* in_sizes, int n_in,
                              void* d_out, int out_size, void* d_ws, size_t ws_size,
                              hipStream_t stream)
{
    const float* x      = (const float*)d_in[0];  // (8,16,128,128)
    const float* theta  = (const float*)d_in[1];  // (1,)
    const float* mean   = (const float*)d_in[2];  // (144,32)
    const float* logsig = (const float*)d_in[3];  // (144,32)
    const float* eps    = (const float*)d_in[4];  // (10,144,32)
    float* out = (float*)d_out;
    unsigned short* W2 = (unsigned short*)d_ws;   // 51200 bf16 = 100 KB

    const int n_w = MC_ * OUT_C_ * KP_;           // 51200
    prep_w_kernel<<<(n_w + 255) / 256, 256, 0, stream>>>(eps, logsig, mean, W2);

    dim3 grid(128, B_);                           // 1024 blocks, all co-resident
    conv_rff_mfma<<<grid, 256, 0, stream>>>(x, W2, theta, out);
}